// Round 8
// baseline (406.521 us; speedup 1.0000x reference)
//
#include <hip/hip_runtime.h>

typedef unsigned short u16;
typedef short s16x8 __attribute__((ext_vector_type(8)));
typedef float f32x4 __attribute__((ext_vector_type(4)));

#define SLOPE 0.01f
#define EPB 64

__device__ __forceinline__ float leaky(float x) { return x >= 0.f ? x : SLOPE * x; }

__device__ __forceinline__ u16 f2b(float f) {          // round-to-nearest-even
    union { float f; unsigned u; } v; v.f = f;
    unsigned r = v.u + 0x7FFFu + ((v.u >> 16) & 1u);
    return (u16)(r >> 16);
}
__device__ __forceinline__ float b2f(u16 b) {
    union { unsigned u; float f; } v; v.u = ((unsigned)b) << 16; return v.f;
}

// ---------------------------------------------------------------------------
// Pass A: histogram active-edge dst counts + mark recv nodes.
// ---------------------------------------------------------------------------
__global__ __launch_bounds__(256) void k_hist(
    const int* __restrict__ src, const int* __restrict__ dst,
    const int* __restrict__ ntype, int* __restrict__ deg,
    float* __restrict__ recvf, int E)
{
    int e = blockIdx.x * 256 + threadIdx.x;
    if (e < E) {
        if (ntype[src[e]] == 2) {
            int d = dst[e];
            atomicAdd(&deg[d], 1);
            recvf[d] = 1.0f;
        }
    }
}

// ---------------------------------------------------------------------------
// Node flag: tflag[i] = (ntype[i]==2)
// ---------------------------------------------------------------------------
__global__ __launch_bounds__(256) void k_flag(
    const int* __restrict__ ntype, int* __restrict__ tflag, int n)
{
    int i = blockIdx.x * 256 + threadIdx.x;
    if (i < n) tflag[i] = (ntype[i] == 2) ? 1 : 0;
}

// ---------------------------------------------------------------------------
// Scan step 1: per-block (256-chunk) sums.
// ---------------------------------------------------------------------------
__global__ __launch_bounds__(256) void k_scan1(
    const int* __restrict__ v, int* __restrict__ bsum, int n)
{
    __shared__ int s[256];
    int i = blockIdx.x * 256 + threadIdx.x;
    s[threadIdx.x] = (i < n) ? v[i] : 0;
    __syncthreads();
    for (int o = 128; o > 0; o >>= 1) {
        if (threadIdx.x < o) s[threadIdx.x] += s[threadIdx.x + o];
        __syncthreads();
    }
    if (threadIdx.x == 0) bsum[blockIdx.x] = s[0];
}

// ---------------------------------------------------------------------------
// Scan step 2: exclusive scan of block sums (nb <= 256) + total.
// ---------------------------------------------------------------------------
__global__ __launch_bounds__(256) void k_scan2(
    int* __restrict__ bsum, int nb, int* __restrict__ totp)
{
    __shared__ int s[256];
    int v = (threadIdx.x < nb) ? bsum[threadIdx.x] : 0;
    s[threadIdx.x] = v;
    __syncthreads();
    for (int o = 1; o < 256; o <<= 1) {
        int x = (threadIdx.x >= o) ? s[threadIdx.x - o] : 0;
        __syncthreads();
        s[threadIdx.x] += x;
        __syncthreads();
    }
    if (threadIdx.x < nb) bsum[threadIdx.x] = s[threadIdx.x] - v;  // exclusive
    if (threadIdx.x == 255) *totp = s[255];                        // total
}

// ---------------------------------------------------------------------------
// Scan step 3: per-element exclusive offsets.
// ---------------------------------------------------------------------------
__global__ __launch_bounds__(256) void k_scan3(
    const int* __restrict__ v, const int* __restrict__ bexcl,
    int* __restrict__ offs, int n)
{
    __shared__ int s[256];
    int i = blockIdx.x * 256 + threadIdx.x;
    int x = (i < n) ? v[i] : 0;
    s[threadIdx.x] = x;
    __syncthreads();
    for (int o = 1; o < 256; o <<= 1) {
        int y = (threadIdx.x >= o) ? s[threadIdx.x - o] : 0;
        __syncthreads();
        s[threadIdx.x] += y;
        __syncthreads();
    }
    if (i < n) offs[i] = bexcl[blockIdx.x] + s[threadIdx.x] - x;
}

// ---------------------------------------------------------------------------
// tlist[trank[i]] = i for task nodes (rank is exact, no atomic needed).
// ---------------------------------------------------------------------------
__global__ __launch_bounds__(256) void k_tlist(
    const int* __restrict__ tflag, const int* __restrict__ trank,
    int* __restrict__ tlist, int n)
{
    int i = blockIdx.x * 256 + threadIdx.x;
    if (i < n && tflag[i]) tlist[trank[i]] = i;
}

// ---------------------------------------------------------------------------
// Pass B: scatter active edges into dst-sorted order via per-dst cursors.
// Stores src as task-node RANK (index into Tsrc).
// ---------------------------------------------------------------------------
__global__ __launch_bounds__(256) void k_scatter_pos(
    const int* __restrict__ src, const int* __restrict__ dst,
    const int* __restrict__ ntype, const int* __restrict__ trank,
    int* __restrict__ cursor, int* __restrict__ eS,
    int* __restrict__ sSg, int* __restrict__ dSg, int E)
{
    int e = blockIdx.x * 256 + threadIdx.x;
    if (e < E) {
        int s = src[e];
        if (ntype[s] == 2) {
            int d = dst[e];
            int p = atomicAdd(&cursor[d], 1);
            eS[p] = e; sSg[p] = trank[s]; dSg[p] = d;
        }
    }
}

// ---------------------------------------------------------------------------
// One-time: gather ef rows into dst-sorted bf16 efS [cnt][64].
// ---------------------------------------------------------------------------
__global__ __launch_bounds__(256) void k_efgather(
    const float* __restrict__ ef, const int* __restrict__ eS,
    const int* __restrict__ cntp, u16* __restrict__ efS)
{
    const int cnt = *cntp;
    const int b0 = blockIdx.x * 64;
    if (b0 >= cnt) return;
    const int t = threadIdx.x;
    #pragma unroll
    for (int pz = 0; pz < 4; ++pz) {
        int idx = t + pz * 256;          // 1024 chunks = 64 edges x 16 float4
        int edge = idx >> 4, f4 = idx & 15;
        int p = b0 + edge;
        if (p < cnt) {
            float4 v = *(const float4*)(ef + (size_t)eS[p] * 64 + f4 * 4);
            ushort4 o;
            o.x = f2b(v.x); o.y = f2b(v.y); o.z = f2b(v.z); o.w = f2b(v.w);
            *(ushort4*)(efS + (size_t)p * 64 + f4 * 4) = o;
        }
    }
}

// ---------------------------------------------------------------------------
// fp32 -> bf16 bulk convert (n multiple of 4)
// ---------------------------------------------------------------------------
__global__ __launch_bounds__(256) void k_f2b(const float* __restrict__ in,
                                             u16* __restrict__ out, int n4)
{
    int i = blockIdx.x * 256 + threadIdx.x;
    if (i < n4) {
        float4 v = ((const float4*)in)[i];
        ushort4 o;
        o.x = f2b(v.x); o.y = f2b(v.y); o.z = f2b(v.z); o.w = f2b(v.w);
        ((ushort4*)out)[i] = o;
    }
}

// ---------------------------------------------------------------------------
// W [K][128] fp32 row-major  ->  WT [128][K] bf16 (n-major)
// ---------------------------------------------------------------------------
__global__ __launch_bounds__(256) void k_wt(const float* __restrict__ W,
                                            u16* __restrict__ WT, int K)
{
    int idx = blockIdx.x * 256 + threadIdx.x;
    if (idx < K * 128) {
        int k = idx >> 7, n = idx & 127;
        WT[n * K + k] = f2b(W[idx]);
    }
}

// ---------------------------------------------------------------------------
// T = A' @ We_half via bf16 MFMA.  A' rows = idx? A[idx[m]] : A[m].
// M = Mp ? *Mp : Mfull (device-side count for the gathered variant).
// Output T [M][128] bf16.
// ---------------------------------------------------------------------------
__global__ __launch_bounds__(256) void k_gemm_T(
    const u16* __restrict__ A, const u16* __restrict__ WT,
    u16* __restrict__ T, const int* __restrict__ idx,
    const int* __restrict__ Mp, int Mfull)
{
    __shared__ u16 As[128][72];
    __shared__ u16 Bs[128][72];
    const int M = Mp ? *Mp : Mfull;
    const int m0 = blockIdx.x * 128;
    if (m0 >= M) return;
    const int t = threadIdx.x;
    const int w = t >> 6, lane = t & 63, wm = w >> 1, wn = w & 1;
    f32x4 acc[4][4] = {};

    const int row = t >> 1, koff = (t & 1) * 32;
    const int gm_s = m0 + row;
    int arow = gm_s;
    if (idx && gm_s < M) arow = idx[gm_s];

    for (int kt = 0; kt < 128; kt += 64) {
        #pragma unroll
        for (int j = 0; j < 4; ++j) {
            int4 va = make_int4(0, 0, 0, 0);
            if (gm_s < M) va = *(const int4*)(A + (size_t)arow * 128 + kt + koff + j * 8);
            *(int4*)&As[row][koff + j * 8] = va;
            *(int4*)&Bs[row][koff + j * 8] =
                *(const int4*)(WT + (size_t)row * 128 + kt + koff + j * 8);
        }
        __syncthreads();
        #pragma unroll
        for (int kf = 0; kf < 2; ++kf) {
            s16x8 a[4], b[4];
            #pragma unroll
            for (int mi = 0; mi < 4; ++mi)
                a[mi] = *(const s16x8*)&As[wm * 64 + mi * 16 + (lane & 15)][kf * 32 + (lane >> 4) * 8];
            #pragma unroll
            for (int ni = 0; ni < 4; ++ni)
                b[ni] = *(const s16x8*)&Bs[wn * 64 + ni * 16 + (lane & 15)][kf * 32 + (lane >> 4) * 8];
            #pragma unroll
            for (int mi = 0; mi < 4; ++mi)
                #pragma unroll
                for (int ni = 0; ni < 4; ++ni)
                    acc[mi][ni] = __builtin_amdgcn_mfma_f32_16x16x32_bf16(
                        a[mi], b[ni], acc[mi][ni], 0, 0, 0);
        }
        __syncthreads();
    }
    const int lr = (lane >> 4) * 4, lc = lane & 15;
    #pragma unroll
    for (int mi = 0; mi < 4; ++mi) {
        #pragma unroll
        for (int r = 0; r < 4; ++r) {
            int gm = m0 + wm * 64 + mi * 16 + lr + r;
            if (gm < M) {
                #pragma unroll
                for (int ni = 0; ni < 4; ++ni)
                    T[(size_t)gm * 128 + wn * 64 + ni * 16 + lc] = f2b(acc[mi][ni][r]);
            }
        }
    }
}

// ---------------------------------------------------------------------------
// out = leaky([H | R] @ Wn) * recv.
// ---------------------------------------------------------------------------
__global__ __launch_bounds__(256) void k_gemm_node(
    const u16* __restrict__ H, const float* __restrict__ R,
    const u16* __restrict__ WT, const float* __restrict__ recvf,
    u16* __restrict__ O16, float* __restrict__ O32, int fin, int M)
{
    __shared__ u16 As[128][72];
    __shared__ u16 Bs[128][72];
    const int t = threadIdx.x;
    const int m0 = blockIdx.x * 128;
    const int w = t >> 6, lane = t & 63, wm = w >> 1, wn = w & 1;
    f32x4 acc[4][4] = {};

    const int row = t >> 1, koff = (t & 1) * 32;
    const int gm_s = m0 + row;

    for (int kt = 0; kt < 256; kt += 64) {
        if (kt < 128) {
            #pragma unroll
            for (int j = 0; j < 4; ++j) {
                int4 va = make_int4(0, 0, 0, 0);
                if (gm_s < M) va = *(const int4*)(H + (size_t)gm_s * 128 + kt + koff + j * 8);
                *(int4*)&As[row][koff + j * 8] = va;
            }
        } else {
            #pragma unroll
            for (int j = 0; j < 8; ++j) {
                float4 v = make_float4(0.f, 0.f, 0.f, 0.f);
                if (gm_s < M) v = *(const float4*)(R + (size_t)gm_s * 128 + (kt - 128) + koff + j * 4);
                ushort4 o;
                o.x = f2b(v.x); o.y = f2b(v.y); o.z = f2b(v.z); o.w = f2b(v.w);
                *(ushort4*)&As[row][koff + j * 4] = o;
            }
        }
        #pragma unroll
        for (int j = 0; j < 4; ++j)
            *(int4*)&Bs[row][koff + j * 8] =
                *(const int4*)(WT + (size_t)row * 256 + kt + koff + j * 8);
        __syncthreads();
        #pragma unroll
        for (int kf = 0; kf < 2; ++kf) {
            s16x8 a[4], b[4];
            #pragma unroll
            for (int mi = 0; mi < 4; ++mi)
                a[mi] = *(const s16x8*)&As[wm * 64 + mi * 16 + (lane & 15)][kf * 32 + (lane >> 4) * 8];
            #pragma unroll
            for (int ni = 0; ni < 4; ++ni)
                b[ni] = *(const s16x8*)&Bs[wn * 64 + ni * 16 + (lane & 15)][kf * 32 + (lane >> 4) * 8];
            #pragma unroll
            for (int mi = 0; mi < 4; ++mi)
                #pragma unroll
                for (int ni = 0; ni < 4; ++ni)
                    acc[mi][ni] = __builtin_amdgcn_mfma_f32_16x16x32_bf16(
                        a[mi], b[ni], acc[mi][ni], 0, 0, 0);
        }
        __syncthreads();
    }
    const int lr = (lane >> 4) * 4, lc = lane & 15;
    #pragma unroll
    for (int mi = 0; mi < 4; ++mi) {
        #pragma unroll
        for (int r = 0; r < 4; ++r) {
            int gm = m0 + wm * 64 + mi * 16 + lr + r;
            if (gm < M) {
                float rv = recvf[gm];
                #pragma unroll
                for (int ni = 0; ni < 4; ++ni) {
                    float val = leaky(acc[mi][ni][r]) * rv;
                    size_t o = (size_t)gm * 128 + wn * 64 + ni * 16 + lc;
                    if (fin) O32[o] = val;
                    else     O16[o] = f2b(val);
                }
            }
        }
    }
}

// ---------------------------------------------------------------------------
// Edge pass over DST-SORTED active edges. efS pre-gathered bf16 (coalesced),
// Tsrc rank-compacted (L2-resident), run-merged coalesced atomics.
// ---------------------------------------------------------------------------
__global__ __launch_bounds__(256) void k_edge(
    const u16* __restrict__ efS, const u16* __restrict__ WTef,  // [128 n][64 k]
    const u16* __restrict__ Tsrc, const u16* __restrict__ Tdst,
    const int* __restrict__ sSg, const int* __restrict__ dSg,
    const int* __restrict__ cntp, float* __restrict__ red)
{
    __shared__ u16 Et[64][72];           // ef tile, edge-major bf16
    __shared__ u16 Ms[64][136];          // msg bf16, edge-major, padded
    __shared__ int sS[EPB], sD[EPB];

    const int t = threadIdx.x;
    const int cnt = *cntp;
    const int b0 = blockIdx.x * EPB;
    if (b0 >= cnt) return;

    if (t < EPB) {
        int p = b0 + t;
        sS[t] = (p < cnt) ? sSg[p] : -1;
        sD[t] = (p < cnt) ? dSg[p] : -1;
    }

    #pragma unroll
    for (int pz = 0; pz < 2; ++pz) {     // stage efS: 512 chunks of 8 bf16
        int idx = t + pz * 256;
        int edge = idx >> 3, c8 = idx & 7;
        int p = b0 + edge;
        int4 v = make_int4(0, 0, 0, 0);
        if (p < cnt) v = *(const int4*)(efS + (size_t)p * 64 + c8 * 8);
        *(int4*)&Et[edge][c8 * 8] = v;
    }
    __syncthreads();

    const int w = t >> 6, lane = t & 63;
    const int lo = lane & 15, q = lane >> 4;
    const int ei = w * 16 + lo;          // this lane's edge slot

    f32x4 acc[8] = {};
    #pragma unroll
    for (int kf = 0; kf < 2; ++kf) {
        s16x8 b = *(const s16x8*)&Et[ei][kf * 32 + q * 8];
        #pragma unroll
        for (int mi = 0; mi < 8; ++mi) {
            s16x8 a = *(const s16x8*)(WTef + (size_t)(mi * 16 + lo) * 64 + kf * 32 + q * 8);
            acc[mi] = __builtin_amdgcn_mfma_f32_16x16x32_bf16(a, b, acc[mi], 0, 0, 0);
        }
    }
    // D mapping: col=lane&15 (edge), row = mi*16 + q*4 + r (feature n)
    #pragma unroll
    for (int mi = 0; mi < 8; ++mi) {
        ushort4 o;
        o.x = f2b(acc[mi][0]); o.y = f2b(acc[mi][1]);
        o.z = f2b(acc[mi][2]); o.w = f2b(acc[mi][3]);
        *(ushort4*)&Ms[ei][mi * 16 + q * 4] = o;
    }
    __syncthreads();

    // scatter: wave w walks its 16 dst-sorted edges; accumulate per same-dst
    // run; one coalesced atomic pair per run.
    float a0 = 0.f, a1 = 0.f;
    int dprev = -1;
    float td0 = 0.f, td1 = 0.f;
    for (int ii = 0; ii < 16; ++ii) {
        int e2 = w * 16 + ii;
        if (b0 + e2 >= cnt) break;
        int d = sD[e2], s = sS[e2];
        if (d != dprev) {
            td0 = b2f(Tdst[(size_t)d * 128 + lane]);
            td1 = b2f(Tdst[(size_t)d * 128 + 64 + lane]);
            dprev = d;
        }
        float t0 = b2f(Tsrc[(size_t)s * 128 + lane]);
        float t1 = b2f(Tsrc[(size_t)s * 128 + 64 + lane]);
        a0 += leaky(b2f(Ms[e2][lane])      + t0 + td0);
        a1 += leaky(b2f(Ms[e2][64 + lane]) + t1 + td1);
        bool last = (ii == 15) || (b0 + e2 + 1 >= cnt) || (sD[e2 + 1] != d);
        if (last) {
            atomicAdd(red + (size_t)d * 128 + lane,      a0);
            atomicAdd(red + (size_t)d * 128 + 64 + lane, a1);
            a0 = 0.f; a1 = 0.f;
        }
    }
}

// ---------------------------------------------------------------------------
extern "C" void kernel_launch(void* const* d_in, const int* in_sizes, int n_in,
                              void* d_out, int out_size, void* d_ws, size_t ws_size,
                              hipStream_t stream)
{
    const float* nf    = (const float*)d_in[0];
    const float* ef    = (const float*)d_in[1];
    const int*   src   = (const int*)d_in[2];
    const int*   dst   = (const int*)d_in[3];
    const int*   ntype = (const int*)d_in[4];
    const float* We[3] = {(const float*)d_in[5], (const float*)d_in[7], (const float*)d_in[9]};
    const float* Wn[3] = {(const float*)d_in[6], (const float*)d_in[8], (const float*)d_in[10]};

    const int N = in_sizes[0] / 128;
    const int E = in_sizes[1] / 64;

    u16* Tsrc = (u16*)d_ws;                        // N*128 (only *tcnt used)
    u16* Tdst = Tsrc + (size_t)N * 128;            // N*128
    u16* hb0  = Tdst + (size_t)N * 128;            // N*128
    u16* hb1  = hb0 + (size_t)N * 128;             // N*128
    u16* WTe  = hb1 + (size_t)N * 128;             // 3*2*16384
    u16* WTn  = WTe + 3 * 2 * 16384;               // 3*32768
    u16* WTef = WTn + 3 * 32768;                   // 3*8192
    u16* efS  = WTef + 3 * 8192;                   // E*64 (only cnt*64 used)
    float* red   = (float*)(efS + (size_t)E * 64); // N*128 fp32
    float* recvf = red + (size_t)N * 128;          // N
    int* deg    = (int*)(recvf + N);               // N
    int* cursor = deg + N;                         // N
    int* tflag  = cursor + N;                      // N
    int* trank  = tflag + N;                       // N
    int* tlist  = trank + N;                       // N
    int* bsum   = tlist + N;                       // 256
    int* bsum2  = bsum + 256;                      // 256
    int* cntp   = bsum2 + 256;                     // 1 (+pad)
    int* tcntp  = cntp + 4;                        // 1 (+pad)
    int* eS     = tcntp + 4;                       // E
    int* sSg    = eS + E;                          // E
    int* dSg    = sSg + E;                         // E

    const int nb  = (N + 255) / 256;               // 196 <= 256 ok
    const int gEb = (E + 255) / 256;

    hipMemsetAsync(deg, 0, (size_t)N * sizeof(int), stream);
    hipMemsetAsync(recvf, 0, (size_t)N * sizeof(float), stream);
    k_hist<<<gEb, 256, 0, stream>>>(src, dst, ntype, deg, recvf, E);
    k_flag<<<nb, 256, 0, stream>>>(ntype, tflag, N);
    // edge-dst scan -> cursor, cnt
    k_scan1<<<nb, 256, 0, stream>>>(deg, bsum, N);
    k_scan2<<<1, 256, 0, stream>>>(bsum, nb, cntp);
    k_scan3<<<nb, 256, 0, stream>>>(deg, bsum, cursor, N);
    // task-node scan -> trank, tcnt
    k_scan1<<<nb, 256, 0, stream>>>(tflag, bsum2, N);
    k_scan2<<<1, 256, 0, stream>>>(bsum2, nb, tcntp);
    k_scan3<<<nb, 256, 0, stream>>>(tflag, bsum2, trank, N);
    k_tlist<<<nb, 256, 0, stream>>>(tflag, trank, tlist, N);
    k_scatter_pos<<<gEb, 256, 0, stream>>>(src, dst, ntype, trank, cursor, eS, sSg, dSg, E);
    k_efgather<<<(E + 63) / 64, 256, 0, stream>>>(ef, eS, cntp, efS);

    // nf -> bf16
    k_f2b<<<(N * 128 / 4 + 255) / 256, 256, 0, stream>>>(nf, hb0, N * 128 / 4);

    // per-layer weight transposes (bf16)
    for (int l = 0; l < 3; ++l) {
        k_wt<<<(128 * 128 + 255) / 256, 256, 0, stream>>>(We[l],             WTe + (size_t)l * 2 * 16384,         128);
        k_wt<<<(128 * 128 + 255) / 256, 256, 0, stream>>>(We[l] + 128 * 128, WTe + (size_t)l * 2 * 16384 + 16384, 128);
        k_wt<<<(256 * 128 + 255) / 256, 256, 0, stream>>>(Wn[l],             WTn + (size_t)l * 32768,             256);
        k_wt<<<(64 * 128 + 255) / 256, 256, 0, stream>>>(We[l] + 256 * 128,  WTef + (size_t)l * 8192,             64);
    }

    dim3 gG((N + 127) / 128);
    int  gE = (E + EPB - 1) / EPB;

    const u16* hIn[3]  = {hb0, hb1, hb0};
    u16*       hOut[3] = {hb1, hb0, hb1};
    for (int l = 0; l < 3; ++l) {
        int fin = (l == 2);
        // src-half over task nodes only (gathered rows, device count)
        k_gemm_T<<<gG, 256, 0, stream>>>(hIn[l], WTe + (size_t)l * 2 * 16384,
                                         Tsrc, tlist, tcntp, N);
        // dst-half over all nodes
        k_gemm_T<<<gG, 256, 0, stream>>>(hIn[l], WTe + (size_t)l * 2 * 16384 + 16384,
                                         Tdst, nullptr, nullptr, N);
        hipMemsetAsync(red, 0, (size_t)N * 128 * sizeof(float), stream);
        k_edge<<<gE, 256, 0, stream>>>(efS, WTef + (size_t)l * 8192, Tsrc, Tdst,
                                       sSg, dSg, cntp, red);
        k_gemm_node<<<gG, 256, 0, stream>>>(hIn[l], red, WTn + (size_t)l * 32768,
                                            recvf, hOut[l], (float*)d_out, fin, N);
    }
}

// Round 9
// 370.570 us; speedup vs baseline: 1.0970x; 1.0970x over previous
//
#include <hip/hip_runtime.h>

typedef unsigned short u16;
typedef short s16x8 __attribute__((ext_vector_type(8)));
typedef float f32x4 __attribute__((ext_vector_type(4)));

#define SLOPE 0.01f
#define EPB 64

__device__ __forceinline__ float leaky(float x) { return x >= 0.f ? x : SLOPE * x; }

__device__ __forceinline__ u16 f2b(float f) {          // round-to-nearest-even
    union { float f; unsigned u; } v; v.f = f;
    unsigned r = v.u + 0x7FFFu + ((v.u >> 16) & 1u);
    return (u16)(r >> 16);
}
__device__ __forceinline__ float b2f(u16 b) {
    union { unsigned u; float f; } v; v.u = ((unsigned)b) << 16; return v.f;
}

// ---------------------------------------------------------------------------
// Init: edge part (deg histogram + recvf mark) and node part (tflag).
// Grid covers E + N threads.
// ---------------------------------------------------------------------------
__global__ __launch_bounds__(256) void k_init(
    const int* __restrict__ src, const int* __restrict__ dst,
    const int* __restrict__ ntype, int* __restrict__ deg,
    float* __restrict__ recvf, int* __restrict__ tflag, int E, int N)
{
    int i = blockIdx.x * 256 + threadIdx.x;
    if (i < E) {
        if (ntype[src[i]] == 2) {
            int d = dst[i];
            atomicAdd(&deg[d], 1);
            recvf[d] = 1.0f;
        }
    } else {
        int j = i - E;
        if (j < N) tflag[j] = (ntype[j] == 2) ? 1 : 0;
    }
}

// ---------------------------------------------------------------------------
// Dual scan step 1: per-256-chunk sums.  y=0: deg->bsum, y=1: tflag->bsum2.
// ---------------------------------------------------------------------------
__global__ __launch_bounds__(256) void k_scan1(
    const int* __restrict__ deg, const int* __restrict__ tflag,
    int* __restrict__ bsum, int* __restrict__ bsum2, int n)
{
    __shared__ int s[256];
    const int* v = blockIdx.y ? tflag : deg;
    int* out = blockIdx.y ? bsum2 : bsum;
    int i = blockIdx.x * 256 + threadIdx.x;
    s[threadIdx.x] = (i < n) ? v[i] : 0;
    __syncthreads();
    for (int o = 128; o > 0; o >>= 1) {
        if (threadIdx.x < o) s[threadIdx.x] += s[threadIdx.x + o];
        __syncthreads();
    }
    if (threadIdx.x == 0) out[blockIdx.x] = s[0];
}

// ---------------------------------------------------------------------------
// Dual scan step 2: exclusive scan of block sums (nb <= 256) + total.
// block 0: (bsum, cntp), block 1: (bsum2, tcntp).
// ---------------------------------------------------------------------------
__global__ __launch_bounds__(256) void k_scan2(
    int* __restrict__ bsum, int* __restrict__ bsum2, int nb,
    int* __restrict__ cntp, int* __restrict__ tcntp)
{
    __shared__ int s[256];
    int* arr = blockIdx.x ? bsum2 : bsum;
    int* tot = blockIdx.x ? tcntp : cntp;
    int v = (threadIdx.x < nb) ? arr[threadIdx.x] : 0;
    s[threadIdx.x] = v;
    __syncthreads();
    for (int o = 1; o < 256; o <<= 1) {
        int x = (threadIdx.x >= o) ? s[threadIdx.x - o] : 0;
        __syncthreads();
        s[threadIdx.x] += x;
        __syncthreads();
    }
    if (threadIdx.x < nb) arr[threadIdx.x] = s[threadIdx.x] - v;  // exclusive
    if (threadIdx.x == 255) *tot = s[255];                        // total
}

// ---------------------------------------------------------------------------
// Dual scan step 3: per-element exclusive offsets.
// y=0: deg -> cursor.  y=1: tflag -> trank, and tlist[trank[i]] = i.
// ---------------------------------------------------------------------------
__global__ __launch_bounds__(256) void k_scan3(
    const int* __restrict__ deg, const int* __restrict__ tflag,
    const int* __restrict__ bsum, const int* __restrict__ bsum2,
    int* __restrict__ cursor, int* __restrict__ trank,
    int* __restrict__ tlist, int n)
{
    __shared__ int s[256];
    const int sel = blockIdx.y;
    const int* v = sel ? tflag : deg;
    const int* bexcl = sel ? bsum2 : bsum;
    int i = blockIdx.x * 256 + threadIdx.x;
    int x = (i < n) ? v[i] : 0;
    s[threadIdx.x] = x;
    __syncthreads();
    for (int o = 1; o < 256; o <<= 1) {
        int y = (threadIdx.x >= o) ? s[threadIdx.x - o] : 0;
        __syncthreads();
        s[threadIdx.x] += y;
        __syncthreads();
    }
    if (i < n) {
        int off = bexcl[blockIdx.x] + s[threadIdx.x] - x;
        if (sel) {
            trank[i] = off;
            if (x) tlist[off] = i;
        } else {
            cursor[i] = off;
        }
    }
}

// ---------------------------------------------------------------------------
// Scatter active edges into dst-sorted order via per-dst cursors.
// Stores src as task-node RANK (index into Tsrc).
// ---------------------------------------------------------------------------
__global__ __launch_bounds__(256) void k_scatter_pos(
    const int* __restrict__ src, const int* __restrict__ dst,
    const int* __restrict__ ntype, const int* __restrict__ trank,
    int* __restrict__ cursor, int* __restrict__ eS,
    int* __restrict__ sSg, int* __restrict__ dSg, int E)
{
    int e = blockIdx.x * 256 + threadIdx.x;
    if (e < E) {
        int s = src[e];
        if (ntype[s] == 2) {
            int d = dst[e];
            int p = atomicAdd(&cursor[d], 1);
            eS[p] = e; sSg[p] = trank[s]; dSg[p] = d;
        }
    }
}

// ---------------------------------------------------------------------------
// One-time: gather ef rows into dst-sorted bf16 efS [cnt][64].
// ---------------------------------------------------------------------------
__global__ __launch_bounds__(256) void k_efgather(
    const float* __restrict__ ef, const int* __restrict__ eS,
    const int* __restrict__ cntp, u16* __restrict__ efS)
{
    const int cnt = *cntp;
    const int b0 = blockIdx.x * 64;
    if (b0 >= cnt) return;
    const int t = threadIdx.x;
    #pragma unroll
    for (int pz = 0; pz < 4; ++pz) {
        int idx = t + pz * 256;          // 1024 chunks = 64 edges x 16 float4
        int edge = idx >> 4, f4 = idx & 15;
        int p = b0 + edge;
        if (p < cnt) {
            float4 v = *(const float4*)(ef + (size_t)eS[p] * 64 + f4 * 4);
            ushort4 o;
            o.x = f2b(v.x); o.y = f2b(v.y); o.z = f2b(v.z); o.w = f2b(v.w);
            *(ushort4*)(efS + (size_t)p * 64 + f4 * 4) = o;
        }
    }
}

// ---------------------------------------------------------------------------
// fp32 -> bf16 bulk convert (n multiple of 4)
// ---------------------------------------------------------------------------
__global__ __launch_bounds__(256) void k_f2b(const float* __restrict__ in,
                                             u16* __restrict__ out, int n4)
{
    int i = blockIdx.x * 256 + threadIdx.x;
    if (i < n4) {
        float4 v = ((const float4*)in)[i];
        ushort4 o;
        o.x = f2b(v.x); o.y = f2b(v.y); o.z = f2b(v.z); o.w = f2b(v.w);
        ((ushort4*)out)[i] = o;
    }
}

// ---------------------------------------------------------------------------
// All weight transposes in ONE kernel.  blockIdx.y = layer.
// Flat idx per layer: [0,32768) We (2 halves, K=128), [32768,65536) Wn (K=256),
// [65536,73728) Wef (K=64, source offset 256*128).
// ---------------------------------------------------------------------------
__global__ __launch_bounds__(256) void k_wt_all(
    const float* __restrict__ We0, const float* __restrict__ We1,
    const float* __restrict__ We2, const float* __restrict__ Wn0,
    const float* __restrict__ Wn1, const float* __restrict__ Wn2,
    u16* __restrict__ WTe, u16* __restrict__ WTn, u16* __restrict__ WTef)
{
    const int l = blockIdx.y;
    const float* We = (l == 0) ? We0 : (l == 1) ? We1 : We2;
    const float* Wn = (l == 0) ? Wn0 : (l == 1) ? Wn1 : Wn2;
    int idx = blockIdx.x * 256 + threadIdx.x;
    if (idx < 32768) {
        int sel = idx >> 14, j = idx & 16383;
        int k = j >> 7, n = j & 127;
        WTe[(size_t)l * 32768 + sel * 16384 + n * 128 + k] = f2b(We[sel * 16384 + j]);
    } else if (idx < 65536) {
        int j = idx - 32768;
        int k = j >> 7, n = j & 127;
        WTn[(size_t)l * 32768 + n * 256 + k] = f2b(Wn[j]);
    } else if (idx < 73728) {
        int j = idx - 65536;
        int k = j >> 7, n = j & 127;
        WTef[(size_t)l * 8192 + n * 64 + k] = f2b(We[32768 + j]);
    }
}

// ---------------------------------------------------------------------------
// Both T halves in one dispatch.  blockIdx.y: 0 = src-half over task ranks
// (A rows gathered via tlist, M = *tcntp), 1 = dst-half over all N rows.
// ---------------------------------------------------------------------------
__global__ __launch_bounds__(256) void k_gemm_T2(
    const u16* __restrict__ A, const u16* __restrict__ WTe_l,
    u16* __restrict__ Tsrc, u16* __restrict__ Tdst,
    const int* __restrict__ tlist, const int* __restrict__ tcntp, int Nfull)
{
    __shared__ u16 As[128][72];
    __shared__ u16 Bs[128][72];
    const int sel = blockIdx.y;
    const int M = sel ? Nfull : *tcntp;
    const int m0 = blockIdx.x * 128;
    if (m0 >= M) return;
    const u16* WT = WTe_l + sel * 16384;
    u16* T = sel ? Tdst : Tsrc;
    const int t = threadIdx.x;
    const int w = t >> 6, lane = t & 63, wm = w >> 1, wn = w & 1;
    f32x4 acc[4][4] = {};

    const int row = t >> 1, koff = (t & 1) * 32;
    const int gm_s = m0 + row;
    int arow = gm_s;
    if (!sel && gm_s < M) arow = tlist[gm_s];

    for (int kt = 0; kt < 128; kt += 64) {
        #pragma unroll
        for (int j = 0; j < 4; ++j) {
            int4 va = make_int4(0, 0, 0, 0);
            if (gm_s < M) va = *(const int4*)(A + (size_t)arow * 128 + kt + koff + j * 8);
            *(int4*)&As[row][koff + j * 8] = va;
            *(int4*)&Bs[row][koff + j * 8] =
                *(const int4*)(WT + (size_t)row * 128 + kt + koff + j * 8);
        }
        __syncthreads();
        #pragma unroll
        for (int kf = 0; kf < 2; ++kf) {
            s16x8 a[4], b[4];
            #pragma unroll
            for (int mi = 0; mi < 4; ++mi)
                a[mi] = *(const s16x8*)&As[wm * 64 + mi * 16 + (lane & 15)][kf * 32 + (lane >> 4) * 8];
            #pragma unroll
            for (int ni = 0; ni < 4; ++ni)
                b[ni] = *(const s16x8*)&Bs[wn * 64 + ni * 16 + (lane & 15)][kf * 32 + (lane >> 4) * 8];
            #pragma unroll
            for (int mi = 0; mi < 4; ++mi)
                #pragma unroll
                for (int ni = 0; ni < 4; ++ni)
                    acc[mi][ni] = __builtin_amdgcn_mfma_f32_16x16x32_bf16(
                        a[mi], b[ni], acc[mi][ni], 0, 0, 0);
        }
        __syncthreads();
    }
    const int lr = (lane >> 4) * 4, lc = lane & 15;
    #pragma unroll
    for (int mi = 0; mi < 4; ++mi) {
        #pragma unroll
        for (int r = 0; r < 4; ++r) {
            int gm = m0 + wm * 64 + mi * 16 + lr + r;
            if (gm < M) {
                #pragma unroll
                for (int ni = 0; ni < 4; ++ni)
                    T[(size_t)gm * 128 + wn * 64 + ni * 16 + lc] = f2b(acc[mi][ni][r]);
            }
        }
    }
}

// ---------------------------------------------------------------------------
// out = leaky([H | R] @ Wn) * recv.  Zeros R in place after staging it
// (each R row is read by exactly one block) -> no per-layer memset needed.
// ---------------------------------------------------------------------------
__global__ __launch_bounds__(256) void k_gemm_node(
    const u16* __restrict__ H, float* __restrict__ R,
    const u16* __restrict__ WT, const float* __restrict__ recvf,
    u16* __restrict__ O16, float* __restrict__ O32, int fin, int M)
{
    __shared__ u16 As[128][72];
    __shared__ u16 Bs[128][72];
    const int t = threadIdx.x;
    const int m0 = blockIdx.x * 128;
    const int w = t >> 6, lane = t & 63, wm = w >> 1, wn = w & 1;
    f32x4 acc[4][4] = {};

    const int row = t >> 1, koff = (t & 1) * 32;
    const int gm_s = m0 + row;

    for (int kt = 0; kt < 256; kt += 64) {
        if (kt < 128) {
            #pragma unroll
            for (int j = 0; j < 4; ++j) {
                int4 va = make_int4(0, 0, 0, 0);
                if (gm_s < M) va = *(const int4*)(H + (size_t)gm_s * 128 + kt + koff + j * 8);
                *(int4*)&As[row][koff + j * 8] = va;
            }
        } else {
            #pragma unroll
            for (int j = 0; j < 8; ++j) {
                float4 v = make_float4(0.f, 0.f, 0.f, 0.f);
                if (gm_s < M) {
                    float* rp = R + (size_t)gm_s * 128 + (kt - 128) + koff + j * 4;
                    v = *(const float4*)rp;
                    *(float4*)rp = make_float4(0.f, 0.f, 0.f, 0.f);  // re-zero for next layer
                }
                ushort4 o;
                o.x = f2b(v.x); o.y = f2b(v.y); o.z = f2b(v.z); o.w = f2b(v.w);
                *(ushort4*)&As[row][koff + j * 4] = o;
            }
        }
        #pragma unroll
        for (int j = 0; j < 4; ++j)
            *(int4*)&Bs[row][koff + j * 8] =
                *(const int4*)(WT + (size_t)row * 256 + kt + koff + j * 8);
        __syncthreads();
        #pragma unroll
        for (int kf = 0; kf < 2; ++kf) {
            s16x8 a[4], b[4];
            #pragma unroll
            for (int mi = 0; mi < 4; ++mi)
                a[mi] = *(const s16x8*)&As[wm * 64 + mi * 16 + (lane & 15)][kf * 32 + (lane >> 4) * 8];
            #pragma unroll
            for (int ni = 0; ni < 4; ++ni)
                b[ni] = *(const s16x8*)&Bs[wn * 64 + ni * 16 + (lane & 15)][kf * 32 + (lane >> 4) * 8];
            #pragma unroll
            for (int mi = 0; mi < 4; ++mi)
                #pragma unroll
                for (int ni = 0; ni < 4; ++ni)
                    acc[mi][ni] = __builtin_amdgcn_mfma_f32_16x16x32_bf16(
                        a[mi], b[ni], acc[mi][ni], 0, 0, 0);
        }
        __syncthreads();
    }
    const int lr = (lane >> 4) * 4, lc = lane & 15;
    #pragma unroll
    for (int mi = 0; mi < 4; ++mi) {
        #pragma unroll
        for (int r = 0; r < 4; ++r) {
            int gm = m0 + wm * 64 + mi * 16 + lr + r;
            if (gm < M) {
                float rv = recvf[gm];
                #pragma unroll
                for (int ni = 0; ni < 4; ++ni) {
                    float val = leaky(acc[mi][ni][r]) * rv;
                    size_t o = (size_t)gm * 128 + wn * 64 + ni * 16 + lc;
                    if (fin) O32[o] = val;
                    else     O16[o] = f2b(val);
                }
            }
        }
    }
}

// ---------------------------------------------------------------------------
// Edge pass over DST-SORTED active edges. efS pre-gathered bf16 (coalesced),
// Tsrc rank-compacted (L2-resident), run-merged coalesced atomics.
// ---------------------------------------------------------------------------
__global__ __launch_bounds__(256) void k_edge(
    const u16* __restrict__ efS, const u16* __restrict__ WTef,  // [128 n][64 k]
    const u16* __restrict__ Tsrc, const u16* __restrict__ Tdst,
    const int* __restrict__ sSg, const int* __restrict__ dSg,
    const int* __restrict__ cntp, float* __restrict__ red)
{
    __shared__ u16 Et[64][72];           // ef tile, edge-major bf16
    __shared__ u16 Ms[64][136];          // msg bf16, edge-major, padded
    __shared__ int sS[EPB], sD[EPB];

    const int t = threadIdx.x;
    const int cnt = *cntp;
    const int b0 = blockIdx.x * EPB;
    if (b0 >= cnt) return;

    if (t < EPB) {
        int p = b0 + t;
        sS[t] = (p < cnt) ? sSg[p] : -1;
        sD[t] = (p < cnt) ? dSg[p] : -1;
    }

    #pragma unroll
    for (int pz = 0; pz < 2; ++pz) {     // stage efS: 512 chunks of 8 bf16
        int idx = t + pz * 256;
        int edge = idx >> 3, c8 = idx & 7;
        int p = b0 + edge;
        int4 v = make_int4(0, 0, 0, 0);
        if (p < cnt) v = *(const int4*)(efS + (size_t)p * 64 + c8 * 8);
        *(int4*)&Et[edge][c8 * 8] = v;
    }
    __syncthreads();

    const int w = t >> 6, lane = t & 63;
    const int lo = lane & 15, q = lane >> 4;
    const int ei = w * 16 + lo;          // this lane's edge slot

    f32x4 acc[8] = {};
    #pragma unroll
    for (int kf = 0; kf < 2; ++kf) {
        s16x8 b = *(const s16x8*)&Et[ei][kf * 32 + q * 8];
        #pragma unroll
        for (int mi = 0; mi < 8; ++mi) {
            s16x8 a = *(const s16x8*)(WTef + (size_t)(mi * 16 + lo) * 64 + kf * 32 + q * 8);
            acc[mi] = __builtin_amdgcn_mfma_f32_16x16x32_bf16(a, b, acc[mi], 0, 0, 0);
        }
    }
    // D mapping: col=lane&15 (edge), row = mi*16 + q*4 + r (feature n)
    #pragma unroll
    for (int mi = 0; mi < 8; ++mi) {
        ushort4 o;
        o.x = f2b(acc[mi][0]); o.y = f2b(acc[mi][1]);
        o.z = f2b(acc[mi][2]); o.w = f2b(acc[mi][3]);
        *(ushort4*)&Ms[ei][mi * 16 + q * 4] = o;
    }
    __syncthreads();

    // scatter: wave w walks its 16 dst-sorted edges; accumulate per same-dst
    // run; one coalesced atomic pair per run.
    float a0 = 0.f, a1 = 0.f;
    int dprev = -1;
    float td0 = 0.f, td1 = 0.f;
    for (int ii = 0; ii < 16; ++ii) {
        int e2 = w * 16 + ii;
        if (b0 + e2 >= cnt) break;
        int d = sD[e2], s = sS[e2];
        if (d != dprev) {
            td0 = b2f(Tdst[(size_t)d * 128 + lane]);
            td1 = b2f(Tdst[(size_t)d * 128 + 64 + lane]);
            dprev = d;
        }
        float t0 = b2f(Tsrc[(size_t)s * 128 + lane]);
        float t1 = b2f(Tsrc[(size_t)s * 128 + 64 + lane]);
        a0 += leaky(b2f(Ms[e2][lane])      + t0 + td0);
        a1 += leaky(b2f(Ms[e2][64 + lane]) + t1 + td1);
        bool last = (ii == 15) || (b0 + e2 + 1 >= cnt) || (sD[e2 + 1] != d);
        if (last) {
            atomicAdd(red + (size_t)d * 128 + lane,      a0);
            atomicAdd(red + (size_t)d * 128 + 64 + lane, a1);
            a0 = 0.f; a1 = 0.f;
        }
    }
}

// ---------------------------------------------------------------------------
extern "C" void kernel_launch(void* const* d_in, const int* in_sizes, int n_in,
                              void* d_out, int out_size, void* d_ws, size_t ws_size,
                              hipStream_t stream)
{
    const float* nf    = (const float*)d_in[0];
    const float* ef    = (const float*)d_in[1];
    const int*   src   = (const int*)d_in[2];
    const int*   dst   = (const int*)d_in[3];
    const int*   ntype = (const int*)d_in[4];
    const float* We[3] = {(const float*)d_in[5], (const float*)d_in[7], (const float*)d_in[9]};
    const float* Wn[3] = {(const float*)d_in[6], (const float*)d_in[8], (const float*)d_in[10]};

    const int N = in_sizes[0] / 128;
    const int E = in_sizes[1] / 64;

    u16* Tsrc = (u16*)d_ws;                        // N*128 (only *tcnt used)
    u16* Tdst = Tsrc + (size_t)N * 128;            // N*128
    u16* hb0  = Tdst + (size_t)N * 128;            // N*128
    u16* hb1  = hb0 + (size_t)N * 128;             // N*128
    u16* WTe  = hb1 + (size_t)N * 128;             // 3*32768
    u16* WTn  = WTe + 3 * 32768;                   // 3*32768
    u16* WTef = WTn + 3 * 32768;                   // 3*8192
    u16* efS  = WTef + 3 * 8192;                   // E*64 (only cnt*64 used)
    float* red   = (float*)(efS + (size_t)E * 64); // N*128 fp32
    float* recvf = red + (size_t)N * 128;          // N   } zeroed together
    int* deg    = (int*)(recvf + N);               // N   }
    int* cursor = deg + N;                         // N
    int* tflag  = cursor + N;                      // N
    int* trank  = tflag + N;                       // N
    int* tlist  = trank + N;                       // N
    int* bsum   = tlist + N;                       // 256
    int* bsum2  = bsum + 256;                      // 256
    int* cntp   = bsum2 + 256;                     // 1 (+pad)
    int* tcntp  = cntp + 4;                        // 1 (+pad)
    int* eS     = tcntp + 4;                       // E
    int* sSg    = eS + E;                          // E
    int* dSg    = sSg + E;                         // E

    const int nb  = (N + 255) / 256;               // 196 <= 256 ok
    const int gEb = (E + 255) / 256;

    // one memset for recvf+deg (adjacent), one for red
    hipMemsetAsync(recvf, 0, (size_t)N * 2 * sizeof(float), stream);
    hipMemsetAsync(red, 0, (size_t)N * 128 * sizeof(float), stream);

    k_init<<<(E + N + 255) / 256, 256, 0, stream>>>(src, dst, ntype, deg, recvf, tflag, E, N);
    k_scan1<<<dim3(nb, 2), 256, 0, stream>>>(deg, tflag, bsum, bsum2, N);
    k_scan2<<<2, 256, 0, stream>>>(bsum, bsum2, nb, cntp, tcntp);
    k_scan3<<<dim3(nb, 2), 256, 0, stream>>>(deg, tflag, bsum, bsum2, cursor, trank, tlist, N);
    k_scatter_pos<<<gEb, 256, 0, stream>>>(src, dst, ntype, trank, cursor, eS, sSg, dSg, E);
    k_efgather<<<(E + 63) / 64, 256, 0, stream>>>(ef, eS, cntp, efS);
    k_f2b<<<(N * 128 / 4 + 255) / 256, 256, 0, stream>>>(nf, hb0, N * 128 / 4);
    k_wt_all<<<dim3(288, 3), 256, 0, stream>>>(We[0], We[1], We[2], Wn[0], Wn[1], Wn[2],
                                               WTe, WTn, WTef);

    dim3 gG((N + 127) / 128);
    dim3 gT((N + 127) / 128, 2);
    int  gE = (E + EPB - 1) / EPB;

    const u16* hIn[3]  = {hb0, hb1, hb0};
    u16*       hOut[3] = {hb1, hb0, hb1};
    for (int l = 0; l < 3; ++l) {
        int fin = (l == 2);
        k_gemm_T2<<<gT, 256, 0, stream>>>(hIn[l], WTe + (size_t)l * 32768,
                                          Tsrc, Tdst, tlist, tcntp, N);
        k_edge<<<gE, 256, 0, stream>>>(efS, WTef + (size_t)l * 8192, Tsrc, Tdst,
                                       sSg, dSg, cntp, red);
        k_gemm_node<<<gG, 256, 0, stream>>>(hIn[l], red, WTn + (size_t)l * 32768,
                                            recvf, hOut[l], (float*)d_out, fin, N);
    }
}

// Round 10
// 364.232 us; speedup vs baseline: 1.1161x; 1.0174x over previous
//
#include <hip/hip_runtime.h>

typedef unsigned short u16;
typedef short s16x8 __attribute__((ext_vector_type(8)));
typedef float f32x4 __attribute__((ext_vector_type(4)));

#define SLOPE 0.01f
#define EPB 64

__device__ __forceinline__ float leaky(float x) { return x >= 0.f ? x : SLOPE * x; }

__device__ __forceinline__ u16 f2b(float f) {          // round-to-nearest-even
    union { float f; unsigned u; } v; v.f = f;
    unsigned r = v.u + 0x7FFFu + ((v.u >> 16) & 1u);
    return (u16)(r >> 16);
}
__device__ __forceinline__ float b2f(u16 b) {
    union { unsigned u; float f; } v; v.u = ((unsigned)b) << 16; return v.f;
}

// ---------------------------------------------------------------------------
// Init: edge part (deg histogram + recvf mark) and node part (tflag).
// ---------------------------------------------------------------------------
__global__ __launch_bounds__(256) void k_init(
    const int* __restrict__ src, const int* __restrict__ dst,
    const int* __restrict__ ntype, int* __restrict__ deg,
    float* __restrict__ recvf, int* __restrict__ tflag, int E, int N)
{
    int i = blockIdx.x * 256 + threadIdx.x;
    if (i < E) {
        if (ntype[src[i]] == 2) {
            int d = dst[i];
            atomicAdd(&deg[d], 1);
            recvf[d] = 1.0f;
        }
    } else {
        int j = i - E;
        if (j < N) tflag[j] = (ntype[j] == 2) ? 1 : 0;
    }
}

// ---------------------------------------------------------------------------
// Dual scan step 1: per-256-chunk sums.  y=0: deg->bsum, y=1: tflag->bsum2.
// ---------------------------------------------------------------------------
__global__ __launch_bounds__(256) void k_scan1(
    const int* __restrict__ deg, const int* __restrict__ tflag,
    int* __restrict__ bsum, int* __restrict__ bsum2, int n)
{
    __shared__ int s[256];
    const int* v = blockIdx.y ? tflag : deg;
    int* out = blockIdx.y ? bsum2 : bsum;
    int i = blockIdx.x * 256 + threadIdx.x;
    s[threadIdx.x] = (i < n) ? v[i] : 0;
    __syncthreads();
    for (int o = 128; o > 0; o >>= 1) {
        if (threadIdx.x < o) s[threadIdx.x] += s[threadIdx.x + o];
        __syncthreads();
    }
    if (threadIdx.x == 0) out[blockIdx.x] = s[0];
}

// ---------------------------------------------------------------------------
// Dual scan step 2: exclusive scan of block sums (nb <= 256) + total.
// ---------------------------------------------------------------------------
__global__ __launch_bounds__(256) void k_scan2(
    int* __restrict__ bsum, int* __restrict__ bsum2, int nb,
    int* __restrict__ cntp, int* __restrict__ tcntp)
{
    __shared__ int s[256];
    int* arr = blockIdx.x ? bsum2 : bsum;
    int* tot = blockIdx.x ? tcntp : cntp;
    int v = (threadIdx.x < nb) ? arr[threadIdx.x] : 0;
    s[threadIdx.x] = v;
    __syncthreads();
    for (int o = 1; o < 256; o <<= 1) {
        int x = (threadIdx.x >= o) ? s[threadIdx.x - o] : 0;
        __syncthreads();
        s[threadIdx.x] += x;
        __syncthreads();
    }
    if (threadIdx.x < nb) arr[threadIdx.x] = s[threadIdx.x] - v;  // exclusive
    if (threadIdx.x == 255) *tot = s[255];                        // total
}

// ---------------------------------------------------------------------------
// Dual scan step 3: per-element exclusive offsets.
// y=0: deg -> cursor.  y=1: tflag -> trank, and tlist[trank[i]] = i.
// ---------------------------------------------------------------------------
__global__ __launch_bounds__(256) void k_scan3(
    const int* __restrict__ deg, const int* __restrict__ tflag,
    const int* __restrict__ bsum, const int* __restrict__ bsum2,
    int* __restrict__ cursor, int* __restrict__ trank,
    int* __restrict__ tlist, int n)
{
    __shared__ int s[256];
    const int sel = blockIdx.y;
    const int* v = sel ? tflag : deg;
    const int* bexcl = sel ? bsum2 : bsum;
    int i = blockIdx.x * 256 + threadIdx.x;
    int x = (i < n) ? v[i] : 0;
    s[threadIdx.x] = x;
    __syncthreads();
    for (int o = 1; o < 256; o <<= 1) {
        int y = (threadIdx.x >= o) ? s[threadIdx.x - o] : 0;
        __syncthreads();
        s[threadIdx.x] += y;
        __syncthreads();
    }
    if (i < n) {
        int off = bexcl[blockIdx.x] + s[threadIdx.x] - x;
        if (sel) {
            trank[i] = off;
            if (x) tlist[off] = i;
        } else {
            cursor[i] = off;
        }
    }
}

// ---------------------------------------------------------------------------
// Scatter active edges into dst-sorted order via per-dst cursors.
// ---------------------------------------------------------------------------
__global__ __launch_bounds__(256) void k_scatter_pos(
    const int* __restrict__ src, const int* __restrict__ dst,
    const int* __restrict__ ntype, const int* __restrict__ trank,
    int* __restrict__ cursor, int* __restrict__ eS,
    int* __restrict__ sSg, int* __restrict__ dSg, int E)
{
    int e = blockIdx.x * 256 + threadIdx.x;
    if (e < E) {
        int s = src[e];
        if (ntype[s] == 2) {
            int d = dst[e];
            int p = atomicAdd(&cursor[d], 1);
            eS[p] = e; sSg[p] = trank[s]; dSg[p] = d;
        }
    }
}

// ---------------------------------------------------------------------------
// One-time: gather ef rows into dst-sorted bf16 efS [cnt][64].
// ---------------------------------------------------------------------------
__global__ __launch_bounds__(256) void k_efgather(
    const float* __restrict__ ef, const int* __restrict__ eS,
    const int* __restrict__ cntp, u16* __restrict__ efS)
{
    const int cnt = *cntp;
    const int b0 = blockIdx.x * 64;
    if (b0 >= cnt) return;
    const int t = threadIdx.x;
    #pragma unroll
    for (int pz = 0; pz < 4; ++pz) {
        int idx = t + pz * 256;          // 1024 chunks = 64 edges x 16 float4
        int edge = idx >> 4, f4 = idx & 15;
        int p = b0 + edge;
        if (p < cnt) {
            float4 v = *(const float4*)(ef + (size_t)eS[p] * 64 + f4 * 4);
            ushort4 o;
            o.x = f2b(v.x); o.y = f2b(v.y); o.z = f2b(v.z); o.w = f2b(v.w);
            *(ushort4*)(efS + (size_t)p * 64 + f4 * 4) = o;
        }
    }
}

// ---------------------------------------------------------------------------
// Prep: nf -> bf16 (first n4 float4 chunks) + all weight transposes (tail).
// Weight flat idx per layer: [0,32768) We halves K=128; [32768,65536) Wn
// K=256; [65536,73728) Wef K=64 (source offset 256*128).
// ---------------------------------------------------------------------------
__global__ __launch_bounds__(256) void k_prep(
    const float* __restrict__ nf, u16* __restrict__ hb0, int n4,
    const float* __restrict__ We0, const float* __restrict__ We1,
    const float* __restrict__ We2, const float* __restrict__ Wn0,
    const float* __restrict__ Wn1, const float* __restrict__ Wn2,
    u16* __restrict__ WTe, u16* __restrict__ WTn, u16* __restrict__ WTef)
{
    int i = blockIdx.x * 256 + threadIdx.x;
    if (i < n4) {
        float4 v = ((const float4*)nf)[i];
        ushort4 o;
        o.x = f2b(v.x); o.y = f2b(v.y); o.z = f2b(v.z); o.w = f2b(v.w);
        ((ushort4*)hb0)[i] = o;
        return;
    }
    int j = i - n4;
    if (j >= 3 * 73728) return;
    int l = j / 73728;
    int idx = j - l * 73728;
    const float* We = (l == 0) ? We0 : (l == 1) ? We1 : We2;
    const float* Wn = (l == 0) ? Wn0 : (l == 1) ? Wn1 : Wn2;
    if (idx < 32768) {
        int sel = idx >> 14, jj = idx & 16383;
        int k = jj >> 7, n = jj & 127;
        WTe[(size_t)l * 32768 + sel * 16384 + n * 128 + k] = f2b(We[sel * 16384 + jj]);
    } else if (idx < 65536) {
        int jj = idx - 32768;
        int k = jj >> 7, n = jj & 127;
        WTn[(size_t)l * 32768 + n * 256 + k] = f2b(Wn[jj]);
    } else {
        int jj = idx - 65536;
        int k = jj >> 7, n = jj & 127;
        WTef[(size_t)l * 8192 + n * 64 + k] = f2b(We[32768 + jj]);
    }
}

// ---------------------------------------------------------------------------
// Both T halves in one dispatch.  blockIdx.y: 0 = src-half over task ranks,
// 1 = dst-half over all N rows.
// ---------------------------------------------------------------------------
__global__ __launch_bounds__(256) void k_gemm_T2(
    const u16* __restrict__ A, const u16* __restrict__ WTe_l,
    u16* __restrict__ Tsrc, u16* __restrict__ Tdst,
    const int* __restrict__ tlist, const int* __restrict__ tcntp, int Nfull)
{
    __shared__ u16 As[128][72];
    __shared__ u16 Bs[128][72];
    const int sel = blockIdx.y;
    const int M = sel ? Nfull : *tcntp;
    const int m0 = blockIdx.x * 128;
    if (m0 >= M) return;
    const u16* WT = WTe_l + sel * 16384;
    u16* T = sel ? Tdst : Tsrc;
    const int t = threadIdx.x;
    const int w = t >> 6, lane = t & 63, wm = w >> 1, wn = w & 1;
    f32x4 acc[4][4] = {};

    const int row = t >> 1, koff = (t & 1) * 32;
    const int gm_s = m0 + row;
    int arow = gm_s;
    if (!sel && gm_s < M) arow = tlist[gm_s];

    for (int kt = 0; kt < 128; kt += 64) {
        #pragma unroll
        for (int j = 0; j < 4; ++j) {
            int4 va = make_int4(0, 0, 0, 0);
            if (gm_s < M) va = *(const int4*)(A + (size_t)arow * 128 + kt + koff + j * 8);
            *(int4*)&As[row][koff + j * 8] = va;
            *(int4*)&Bs[row][koff + j * 8] =
                *(const int4*)(WT + (size_t)row * 128 + kt + koff + j * 8);
        }
        __syncthreads();
        #pragma unroll
        for (int kf = 0; kf < 2; ++kf) {
            s16x8 a[4], b[4];
            #pragma unroll
            for (int mi = 0; mi < 4; ++mi)
                a[mi] = *(const s16x8*)&As[wm * 64 + mi * 16 + (lane & 15)][kf * 32 + (lane >> 4) * 8];
            #pragma unroll
            for (int ni = 0; ni < 4; ++ni)
                b[ni] = *(const s16x8*)&Bs[wn * 64 + ni * 16 + (lane & 15)][kf * 32 + (lane >> 4) * 8];
            #pragma unroll
            for (int mi = 0; mi < 4; ++mi)
                #pragma unroll
                for (int ni = 0; ni < 4; ++ni)
                    acc[mi][ni] = __builtin_amdgcn_mfma_f32_16x16x32_bf16(
                        a[mi], b[ni], acc[mi][ni], 0, 0, 0);
        }
        __syncthreads();
    }
    const int lr = (lane >> 4) * 4, lc = lane & 15;
    #pragma unroll
    for (int mi = 0; mi < 4; ++mi) {
        #pragma unroll
        for (int r = 0; r < 4; ++r) {
            int gm = m0 + wm * 64 + mi * 16 + lr + r;
            if (gm < M) {
                #pragma unroll
                for (int ni = 0; ni < 4; ++ni)
                    T[(size_t)gm * 128 + wn * 64 + ni * 16 + lc] = f2b(acc[mi][ni][r]);
            }
        }
    }
}

// ---------------------------------------------------------------------------
// out = leaky([H | R] @ Wn) * recv.  Zeros R in place after staging it.
// ---------------------------------------------------------------------------
__global__ __launch_bounds__(256) void k_gemm_node(
    const u16* __restrict__ H, float* __restrict__ R,
    const u16* __restrict__ WT, const float* __restrict__ recvf,
    u16* __restrict__ O16, float* __restrict__ O32, int fin, int M)
{
    __shared__ u16 As[128][72];
    __shared__ u16 Bs[128][72];
    const int t = threadIdx.x;
    const int m0 = blockIdx.x * 128;
    const int w = t >> 6, lane = t & 63, wm = w >> 1, wn = w & 1;
    f32x4 acc[4][4] = {};

    const int row = t >> 1, koff = (t & 1) * 32;
    const int gm_s = m0 + row;

    for (int kt = 0; kt < 256; kt += 64) {
        if (kt < 128) {
            #pragma unroll
            for (int j = 0; j < 4; ++j) {
                int4 va = make_int4(0, 0, 0, 0);
                if (gm_s < M) va = *(const int4*)(H + (size_t)gm_s * 128 + kt + koff + j * 8);
                *(int4*)&As[row][koff + j * 8] = va;
            }
        } else {
            #pragma unroll
            for (int j = 0; j < 8; ++j) {
                float4 v = make_float4(0.f, 0.f, 0.f, 0.f);
                if (gm_s < M) {
                    float* rp = R + (size_t)gm_s * 128 + (kt - 128) + koff + j * 4;
                    v = *(const float4*)rp;
                    *(float4*)rp = make_float4(0.f, 0.f, 0.f, 0.f);  // re-zero for next layer
                }
                ushort4 o;
                o.x = f2b(v.x); o.y = f2b(v.y); o.z = f2b(v.z); o.w = f2b(v.w);
                *(ushort4*)&As[row][koff + j * 4] = o;
            }
        }
        #pragma unroll
        for (int j = 0; j < 4; ++j)
            *(int4*)&Bs[row][koff + j * 8] =
                *(const int4*)(WT + (size_t)row * 256 + kt + koff + j * 8);
        __syncthreads();
        #pragma unroll
        for (int kf = 0; kf < 2; ++kf) {
            s16x8 a[4], b[4];
            #pragma unroll
            for (int mi = 0; mi < 4; ++mi)
                a[mi] = *(const s16x8*)&As[wm * 64 + mi * 16 + (lane & 15)][kf * 32 + (lane >> 4) * 8];
            #pragma unroll
            for (int ni = 0; ni < 4; ++ni)
                b[ni] = *(const s16x8*)&Bs[wn * 64 + ni * 16 + (lane & 15)][kf * 32 + (lane >> 4) * 8];
            #pragma unroll
            for (int mi = 0; mi < 4; ++mi)
                #pragma unroll
                for (int ni = 0; ni < 4; ++ni)
                    acc[mi][ni] = __builtin_amdgcn_mfma_f32_16x16x32_bf16(
                        a[mi], b[ni], acc[mi][ni], 0, 0, 0);
        }
        __syncthreads();
    }
    const int lr = (lane >> 4) * 4, lc = lane & 15;
    #pragma unroll
    for (int mi = 0; mi < 4; ++mi) {
        #pragma unroll
        for (int r = 0; r < 4; ++r) {
            int gm = m0 + wm * 64 + mi * 16 + lr + r;
            if (gm < M) {
                float rv = recvf[gm];
                #pragma unroll
                for (int ni = 0; ni < 4; ++ni) {
                    float val = leaky(acc[mi][ni][r]) * rv;
                    size_t o = (size_t)gm * 128 + wn * 64 + ni * 16 + lc;
                    if (fin) O32[o] = val;
                    else     O16[o] = f2b(val);
                }
            }
        }
    }
}

// ---------------------------------------------------------------------------
// Edge pass, 512 threads: waves 0-3 do the MFMA matvec (efS B-operand read
// straight from global — each element used exactly once per block); all 8
// waves scatter 8 edges each (serial chain halved vs 4-wave version).
// ---------------------------------------------------------------------------
__global__ __launch_bounds__(512) void k_edge(
    const u16* __restrict__ efS, const u16* __restrict__ WTef,  // [128 n][64 k]
    const u16* __restrict__ Tsrc, const u16* __restrict__ Tdst,
    const int* __restrict__ sSg, const int* __restrict__ dSg,
    const int* __restrict__ cntp, float* __restrict__ red)
{
    __shared__ u16 Ms[64][136];          // msg bf16, edge-major, padded
    __shared__ int sS[EPB], sD[EPB];

    const int t = threadIdx.x;
    const int cnt = *cntp;
    const int b0 = blockIdx.x * EPB;
    if (b0 >= cnt) return;

    if (t < EPB) {
        int p = b0 + t;
        sS[t] = (p < cnt) ? sSg[p] : -1;
        sD[t] = (p < cnt) ? dSg[p] : -1;
    }

    const int w = t >> 6, lane = t & 63;
    const int lo = lane & 15, q = lane >> 4;

    if (w < 4) {
        const int ei = w * 16 + lo;      // this lane's edge slot
        const int p = b0 + ei;
        f32x4 acc[8] = {};
        #pragma unroll
        for (int kf = 0; kf < 2; ++kf) {
            s16x8 b = {};
            if (p < cnt) b = *(const s16x8*)(efS + (size_t)p * 64 + kf * 32 + q * 8);
            #pragma unroll
            for (int mi = 0; mi < 8; ++mi) {
                s16x8 a = *(const s16x8*)(WTef + (size_t)(mi * 16 + lo) * 64 + kf * 32 + q * 8);
                acc[mi] = __builtin_amdgcn_mfma_f32_16x16x32_bf16(a, b, acc[mi], 0, 0, 0);
            }
        }
        // D mapping: col=lane&15 (edge), row = mi*16 + q*4 + r (feature n)
        #pragma unroll
        for (int mi = 0; mi < 8; ++mi) {
            ushort4 o;
            o.x = f2b(acc[mi][0]); o.y = f2b(acc[mi][1]);
            o.z = f2b(acc[mi][2]); o.w = f2b(acc[mi][3]);
            *(ushort4*)&Ms[ei][mi * 16 + q * 4] = o;
        }
    }
    __syncthreads();

    // scatter: wave w walks its 8 dst-sorted edges; accumulate per same-dst
    // run; one coalesced atomic pair per run.
    float a0 = 0.f, a1 = 0.f;
    int dprev = -1;
    float td0 = 0.f, td1 = 0.f;
    for (int ii = 0; ii < 8; ++ii) {
        int e2 = w * 8 + ii;
        if (b0 + e2 >= cnt) break;
        int d = sD[e2], s = sS[e2];
        if (d != dprev) {
            td0 = b2f(Tdst[(size_t)d * 128 + lane]);
            td1 = b2f(Tdst[(size_t)d * 128 + 64 + lane]);
            dprev = d;
        }
        float t0 = b2f(Tsrc[(size_t)s * 128 + lane]);
        float t1 = b2f(Tsrc[(size_t)s * 128 + 64 + lane]);
        a0 += leaky(b2f(Ms[e2][lane])      + t0 + td0);
        a1 += leaky(b2f(Ms[e2][64 + lane]) + t1 + td1);
        bool last = (ii == 7) || (b0 + e2 + 1 >= cnt) || (sD[e2 + 1] != d);
        if (last) {
            atomicAdd(red + (size_t)d * 128 + lane,      a0);
            atomicAdd(red + (size_t)d * 128 + 64 + lane, a1);
            a0 = 0.f; a1 = 0.f;
        }
    }
}

// ---------------------------------------------------------------------------
extern "C" void kernel_launch(void* const* d_in, const int* in_sizes, int n_in,
                              void* d_out, int out_size, void* d_ws, size_t ws_size,
                              hipStream_t stream)
{
    const float* nf    = (const float*)d_in[0];
    const float* ef    = (const float*)d_in[1];
    const int*   src   = (const int*)d_in[2];
    const int*   dst   = (const int*)d_in[3];
    const int*   ntype = (const int*)d_in[4];
    const float* We[3] = {(const float*)d_in[5], (const float*)d_in[7], (const float*)d_in[9]};
    const float* Wn[3] = {(const float*)d_in[6], (const float*)d_in[8], (const float*)d_in[10]};

    const int N = in_sizes[0] / 128;
    const int E = in_sizes[1] / 64;

    u16* Tsrc = (u16*)d_ws;                        // N*128 (only *tcnt used)
    u16* Tdst = Tsrc + (size_t)N * 128;            // N*128
    u16* hb0  = Tdst + (size_t)N * 128;            // N*128
    u16* hb1  = hb0 + (size_t)N * 128;             // N*128
    u16* WTe  = hb1 + (size_t)N * 128;             // 3*32768
    u16* WTn  = WTe + 3 * 32768;                   // 3*32768
    u16* WTef = WTn + 3 * 32768;                   // 3*8192
    u16* efS  = WTef + 3 * 8192;                   // E*64 (only cnt*64 used)
    float* red   = (float*)(efS + (size_t)E * 64); // N*128 fp32
    float* recvf = red + (size_t)N * 128;          // N   } zeroed together
    int* deg    = (int*)(recvf + N);               // N   }
    int* cursor = deg + N;                         // N
    int* tflag  = cursor + N;                      // N
    int* trank  = tflag + N;                       // N
    int* tlist  = trank + N;                       // N
    int* bsum   = tlist + N;                       // 256
    int* bsum2  = bsum + 256;                      // 256
    int* cntp   = bsum2 + 256;                     // 1 (+pad)
    int* tcntp  = cntp + 4;                        // 1 (+pad)
    int* eS     = tcntp + 4;                       // E
    int* sSg    = eS + E;                          // E
    int* dSg    = sSg + E;                         // E

    const int nb  = (N + 255) / 256;               // 196 <= 256 ok
    const int gEb = (E + 255) / 256;
    const int n4  = N * 128 / 4;

    hipMemsetAsync(recvf, 0, (size_t)N * 2 * sizeof(float), stream);
    hipMemsetAsync(red, 0, (size_t)N * 128 * sizeof(float), stream);

    k_init<<<(E + N + 255) / 256, 256, 0, stream>>>(src, dst, ntype, deg, recvf, tflag, E, N);
    k_scan1<<<dim3(nb, 2), 256, 0, stream>>>(deg, tflag, bsum, bsum2, N);
    k_scan2<<<2, 256, 0, stream>>>(bsum, bsum2, nb, cntp, tcntp);
    k_scan3<<<dim3(nb, 2), 256, 0, stream>>>(deg, tflag, bsum, bsum2, cursor, trank, tlist, N);
    k_scatter_pos<<<gEb, 256, 0, stream>>>(src, dst, ntype, trank, cursor, eS, sSg, dSg, E);
    k_efgather<<<(E + 63) / 64, 256, 0, stream>>>(ef, eS, cntp, efS);
    k_prep<<<(n4 + 3 * 73728 + 255) / 256, 256, 0, stream>>>(
        nf, hb0, n4, We[0], We[1], We[2], Wn[0], Wn[1], Wn[2], WTe, WTn, WTef);

    dim3 gG((N + 127) / 128);
    dim3 gT((N + 127) / 128, 2);
    int  gE = (E + EPB - 1) / EPB;

    const u16* hIn[3]  = {hb0, hb1, hb0};
    u16*       hOut[3] = {hb1, hb0, hb1};
    for (int l = 0; l < 3; ++l) {
        int fin = (l == 2);
        k_gemm_T2<<<gT, 256, 0, stream>>>(hIn[l], WTe + (size_t)l * 32768,
                                          Tsrc, Tdst, tlist, tcntp, N);
        k_edge<<<gE, 512, 0, stream>>>(efS, WTef + (size_t)l * 8192, Tsrc, Tdst,
                                       sSg, dSg, cntp, red);
        k_gemm_node<<<gG, 256, 0, stream>>>(hIn[l], red, WTn + (size_t)l * 32768,
                                            recvf, hOut[l], (float*)d_out, fin, N);
    }
}

// Round 11
// 342.718 us; speedup vs baseline: 1.1862x; 1.0628x over previous
//
#include <hip/hip_runtime.h>

typedef unsigned short u16;
typedef short s16x8 __attribute__((ext_vector_type(8)));
typedef float f32x4 __attribute__((ext_vector_type(4)));

#define SLOPE 0.01f
#define EPB 64

__device__ __forceinline__ float leaky(float x) { return x >= 0.f ? x : SLOPE * x; }

__device__ __forceinline__ u16 f2b(float f) {          // round-to-nearest-even
    union { float f; unsigned u; } v; v.f = f;
    unsigned r = v.u + 0x7FFFu + ((v.u >> 16) & 1u);
    return (u16)(r >> 16);
}
__device__ __forceinline__ float b2f(u16 b) {
    union { unsigned u; float f; } v; v.u = ((unsigned)b) << 16; return v.f;
}

// ---------------------------------------------------------------------------
// Init: edge part (deg histogram + recvf mark) and node part (tflag).
// ---------------------------------------------------------------------------
__global__ __launch_bounds__(256) void k_init(
    const int* __restrict__ src, const int* __restrict__ dst,
    const int* __restrict__ ntype, int* __restrict__ deg,
    float* __restrict__ recvf, int* __restrict__ tflag, int E, int N)
{
    int i = blockIdx.x * 256 + threadIdx.x;
    if (i < E) {
        if (ntype[src[i]] == 2) {
            int d = dst[i];
            atomicAdd(&deg[d], 1);
            recvf[d] = 1.0f;
        }
    } else {
        int j = i - E;
        if (j < N) tflag[j] = (ntype[j] == 2) ? 1 : 0;
    }
}

// ---------------------------------------------------------------------------
// Dual scan step 1: per-256-chunk sums.  y=0: deg->bsum, y=1: tflag->bsum2.
// ---------------------------------------------------------------------------
__global__ __launch_bounds__(256) void k_scan1(
    const int* __restrict__ deg, const int* __restrict__ tflag,
    int* __restrict__ bsum, int* __restrict__ bsum2, int n)
{
    __shared__ int s[256];
    const int* v = blockIdx.y ? tflag : deg;
    int* out = blockIdx.y ? bsum2 : bsum;
    int i = blockIdx.x * 256 + threadIdx.x;
    s[threadIdx.x] = (i < n) ? v[i] : 0;
    __syncthreads();
    for (int o = 128; o > 0; o >>= 1) {
        if (threadIdx.x < o) s[threadIdx.x] += s[threadIdx.x + o];
        __syncthreads();
    }
    if (threadIdx.x == 0) out[blockIdx.x] = s[0];
}

// ---------------------------------------------------------------------------
// Dual scan step 2: exclusive scan of block sums (nb <= 256) + total.
// ---------------------------------------------------------------------------
__global__ __launch_bounds__(256) void k_scan2(
    int* __restrict__ bsum, int* __restrict__ bsum2, int nb,
    int* __restrict__ cntp, int* __restrict__ tcntp)
{
    __shared__ int s[256];
    int* arr = blockIdx.x ? bsum2 : bsum;
    int* tot = blockIdx.x ? tcntp : cntp;
    int v = (threadIdx.x < nb) ? arr[threadIdx.x] : 0;
    s[threadIdx.x] = v;
    __syncthreads();
    for (int o = 1; o < 256; o <<= 1) {
        int x = (threadIdx.x >= o) ? s[threadIdx.x - o] : 0;
        __syncthreads();
        s[threadIdx.x] += x;
        __syncthreads();
    }
    if (threadIdx.x < nb) arr[threadIdx.x] = s[threadIdx.x] - v;  // exclusive
    if (threadIdx.x == 255) *tot = s[255];                        // total
}

// ---------------------------------------------------------------------------
// Dual scan step 3: per-element exclusive offsets.
// y=0: deg -> cursor.  y=1: tflag -> trank, and tlist[trank[i]] = i.
// ---------------------------------------------------------------------------
__global__ __launch_bounds__(256) void k_scan3(
    const int* __restrict__ deg, const int* __restrict__ tflag,
    const int* __restrict__ bsum, const int* __restrict__ bsum2,
    int* __restrict__ cursor, int* __restrict__ trank,
    int* __restrict__ tlist, int n)
{
    __shared__ int s[256];
    const int sel = blockIdx.y;
    const int* v = sel ? tflag : deg;
    const int* bexcl = sel ? bsum2 : bsum;
    int i = blockIdx.x * 256 + threadIdx.x;
    int x = (i < n) ? v[i] : 0;
    s[threadIdx.x] = x;
    __syncthreads();
    for (int o = 1; o < 256; o <<= 1) {
        int y = (threadIdx.x >= o) ? s[threadIdx.x - o] : 0;
        __syncthreads();
        s[threadIdx.x] += y;
        __syncthreads();
    }
    if (i < n) {
        int off = bexcl[blockIdx.x] + s[threadIdx.x] - x;
        if (sel) {
            trank[i] = off;
            if (x) tlist[off] = i;
        } else {
            cursor[i] = off;
        }
    }
}

// ---------------------------------------------------------------------------
// Scatter active edges into dst-sorted order via per-dst cursors.
// After this kernel, cursor[d] = END offset of d's segment (start = end-deg).
// ---------------------------------------------------------------------------
__global__ __launch_bounds__(256) void k_scatter_pos(
    const int* __restrict__ src, const int* __restrict__ dst,
    const int* __restrict__ ntype, const int* __restrict__ trank,
    int* __restrict__ cursor, int* __restrict__ eS,
    int* __restrict__ sSg, int E)
{
    int e = blockIdx.x * 256 + threadIdx.x;
    if (e < E) {
        int s = src[e];
        if (ntype[s] == 2) {
            int d = dst[e];
            int p = atomicAdd(&cursor[d], 1);
            eS[p] = e; sSg[p] = trank[s];
        }
    }
}

// ---------------------------------------------------------------------------
// One-time: gather ef rows into dst-sorted bf16 efS [cnt][64].
// ---------------------------------------------------------------------------
__global__ __launch_bounds__(256) void k_efgather(
    const float* __restrict__ ef, const int* __restrict__ eS,
    const int* __restrict__ cntp, u16* __restrict__ efS)
{
    const int cnt = *cntp;
    const int b0 = blockIdx.x * 64;
    if (b0 >= cnt) return;
    const int t = threadIdx.x;
    #pragma unroll
    for (int pz = 0; pz < 4; ++pz) {
        int idx = t + pz * 256;          // 1024 chunks = 64 edges x 16 float4
        int edge = idx >> 4, f4 = idx & 15;
        int p = b0 + edge;
        if (p < cnt) {
            float4 v = *(const float4*)(ef + (size_t)eS[p] * 64 + f4 * 4);
            ushort4 o;
            o.x = f2b(v.x); o.y = f2b(v.y); o.z = f2b(v.z); o.w = f2b(v.w);
            *(ushort4*)(efS + (size_t)p * 64 + f4 * 4) = o;
        }
    }
}

// ---------------------------------------------------------------------------
// Prep: nf -> bf16 (first n4 float4 chunks) + all weight transposes (tail).
// ---------------------------------------------------------------------------
__global__ __launch_bounds__(256) void k_prep(
    const float* __restrict__ nf, u16* __restrict__ hb0, int n4,
    const float* __restrict__ We0, const float* __restrict__ We1,
    const float* __restrict__ We2, const float* __restrict__ Wn0,
    const float* __restrict__ Wn1, const float* __restrict__ Wn2,
    u16* __restrict__ WTe, u16* __restrict__ WTn, u16* __restrict__ WTef)
{
    int i = blockIdx.x * 256 + threadIdx.x;
    if (i < n4) {
        float4 v = ((const float4*)nf)[i];
        ushort4 o;
        o.x = f2b(v.x); o.y = f2b(v.y); o.z = f2b(v.z); o.w = f2b(v.w);
        ((ushort4*)hb0)[i] = o;
        return;
    }
    int j = i - n4;
    if (j >= 3 * 73728) return;
    int l = j / 73728;
    int idx = j - l * 73728;
    const float* We = (l == 0) ? We0 : (l == 1) ? We1 : We2;
    const float* Wn = (l == 0) ? Wn0 : (l == 1) ? Wn1 : Wn2;
    if (idx < 32768) {
        int sel = idx >> 14, jj = idx & 16383;
        int k = jj >> 7, n = jj & 127;
        WTe[(size_t)l * 32768 + sel * 16384 + n * 128 + k] = f2b(We[sel * 16384 + jj]);
    } else if (idx < 65536) {
        int jj = idx - 32768;
        int k = jj >> 7, n = jj & 127;
        WTn[(size_t)l * 32768 + n * 256 + k] = f2b(Wn[jj]);
    } else {
        int jj = idx - 65536;
        int k = jj >> 7, n = jj & 127;
        WTef[(size_t)l * 8192 + n * 64 + k] = f2b(We[32768 + jj]);
    }
}

// ---------------------------------------------------------------------------
// Both T halves in one dispatch.  blockIdx.y: 0 = src-half over task ranks,
// 1 = dst-half over all N rows.
// ---------------------------------------------------------------------------
__global__ __launch_bounds__(256) void k_gemm_T2(
    const u16* __restrict__ A, const u16* __restrict__ WTe_l,
    u16* __restrict__ Tsrc, u16* __restrict__ Tdst,
    const int* __restrict__ tlist, const int* __restrict__ tcntp, int Nfull)
{
    __shared__ u16 As[128][72];
    __shared__ u16 Bs[128][72];
    const int sel = blockIdx.y;
    const int M = sel ? Nfull : *tcntp;
    const int m0 = blockIdx.x * 128;
    if (m0 >= M) return;
    const u16* WT = WTe_l + sel * 16384;
    u16* T = sel ? Tdst : Tsrc;
    const int t = threadIdx.x;
    const int w = t >> 6, lane = t & 63, wm = w >> 1, wn = w & 1;
    f32x4 acc[4][4] = {};

    const int row = t >> 1, koff = (t & 1) * 32;
    const int gm_s = m0 + row;
    int arow = gm_s;
    if (!sel && gm_s < M) arow = tlist[gm_s];

    for (int kt = 0; kt < 128; kt += 64) {
        #pragma unroll
        for (int j = 0; j < 4; ++j) {
            int4 va = make_int4(0, 0, 0, 0);
            if (gm_s < M) va = *(const int4*)(A + (size_t)arow * 128 + kt + koff + j * 8);
            *(int4*)&As[row][koff + j * 8] = va;
            *(int4*)&Bs[row][koff + j * 8] =
                *(const int4*)(WT + (size_t)row * 128 + kt + koff + j * 8);
        }
        __syncthreads();
        #pragma unroll
        for (int kf = 0; kf < 2; ++kf) {
            s16x8 a[4], b[4];
            #pragma unroll
            for (int mi = 0; mi < 4; ++mi)
                a[mi] = *(const s16x8*)&As[wm * 64 + mi * 16 + (lane & 15)][kf * 32 + (lane >> 4) * 8];
            #pragma unroll
            for (int ni = 0; ni < 4; ++ni)
                b[ni] = *(const s16x8*)&Bs[wn * 64 + ni * 16 + (lane & 15)][kf * 32 + (lane >> 4) * 8];
            #pragma unroll
            for (int mi = 0; mi < 4; ++mi)
                #pragma unroll
                for (int ni = 0; ni < 4; ++ni)
                    acc[mi][ni] = __builtin_amdgcn_mfma_f32_16x16x32_bf16(
                        a[mi], b[ni], acc[mi][ni], 0, 0, 0);
        }
        __syncthreads();
    }
    const int lr = (lane >> 4) * 4, lc = lane & 15;
    #pragma unroll
    for (int mi = 0; mi < 4; ++mi) {
        #pragma unroll
        for (int r = 0; r < 4; ++r) {
            int gm = m0 + wm * 64 + mi * 16 + lr + r;
            if (gm < M) {
                #pragma unroll
                for (int ni = 0; ni < 4; ++ni)
                    T[(size_t)gm * 128 + wn * 64 + ni * 16 + lc] = f2b(acc[mi][ni][r]);
            }
        }
    }
}

// ---------------------------------------------------------------------------
// Edge matvec only: msgS[p][128] = (ef[p] @ We_ef) via MFMA, coalesced out.
// 64 sorted edges per block, 4 waves.
// ---------------------------------------------------------------------------
__global__ __launch_bounds__(256) void k_msg(
    const u16* __restrict__ efS, const u16* __restrict__ WTef,  // [128 n][64 k]
    const int* __restrict__ cntp, u16* __restrict__ msgS)
{
    __shared__ u16 Ms[64][136];
    const int cnt = *cntp;
    const int b0 = blockIdx.x * EPB;
    if (b0 >= cnt) return;
    const int t = threadIdx.x;
    const int w = t >> 6, lane = t & 63;
    const int lo = lane & 15, q = lane >> 4;
    const int ei = w * 16 + lo;
    const int p = b0 + ei;

    f32x4 acc[8] = {};
    #pragma unroll
    for (int kf = 0; kf < 2; ++kf) {
        s16x8 b = {};
        if (p < cnt) b = *(const s16x8*)(efS + (size_t)p * 64 + kf * 32 + q * 8);
        #pragma unroll
        for (int mi = 0; mi < 8; ++mi) {
            s16x8 a = *(const s16x8*)(WTef + (size_t)(mi * 16 + lo) * 64 + kf * 32 + q * 8);
            acc[mi] = __builtin_amdgcn_mfma_f32_16x16x32_bf16(a, b, acc[mi], 0, 0, 0);
        }
    }
    // D mapping: col=lane&15 (edge), row = mi*16 + q*4 + r (feature n)
    #pragma unroll
    for (int mi = 0; mi < 8; ++mi) {
        ushort4 o;
        o.x = f2b(acc[mi][0]); o.y = f2b(acc[mi][1]);
        o.z = f2b(acc[mi][2]); o.w = f2b(acc[mi][3]);
        *(ushort4*)&Ms[ei][mi * 16 + q * 4] = o;
    }
    __syncthreads();
    // coalesced stream-out: 1024 int4 chunks (64 edges x 16)
    #pragma unroll
    for (int pz = 0; pz < 4; ++pz) {
        int idx = t + pz * 256;
        int row = idx >> 4, c8 = idx & 15;
        int pp = b0 + row;
        if (pp < cnt)
            *(int4*)(msgS + (size_t)pp * 128 + c8 * 8) = *(const int4*)&Ms[row][c8 * 8];
    }
}

// ---------------------------------------------------------------------------
// CSR segmented reduce: one wave per dst node, NO atomics, plain bf16 store.
//   red[d] = sum_{i in seg(d)} leaky(msg[i] + Tsrc[sSg[i]] + Tdst[d])
// Each lane owns 2 features (2*lane, 2*lane+1) packed in one u32.
// ---------------------------------------------------------------------------
__global__ __launch_bounds__(256) void k_reduce(
    const u16* __restrict__ msgS, const u16* __restrict__ Tsrc,
    const u16* __restrict__ Tdst, const int* __restrict__ sSg,
    const int* __restrict__ deg, const int* __restrict__ segEnd,
    u16* __restrict__ redb, int N)
{
    const int w = threadIdx.x >> 6, lane = threadIdx.x & 63;
    const int d = blockIdx.x * 4 + w;
    if (d >= N) return;
    const int dg = deg[d];
    if (dg == 0) return;                 // recv=0 masks these rows downstream
    const int end = segEnd[d], beg = end - dg;

    unsigned td = *(const unsigned*)(Tdst + (size_t)d * 128 + lane * 2);
    const float td0 = b2f((u16)(td & 0xffff)), td1 = b2f((u16)(td >> 16));
    float a0 = 0.f, a1 = 0.f;
    for (int i = beg; i < end; ++i) {
        int s = sSg[i];                  // uniform across wave -> broadcast
        unsigned m  = *(const unsigned*)(msgS + (size_t)i * 128 + lane * 2);
        unsigned ts = *(const unsigned*)(Tsrc + (size_t)s * 128 + lane * 2);
        a0 += leaky(b2f((u16)(m & 0xffff)) + b2f((u16)(ts & 0xffff)) + td0);
        a1 += leaky(b2f((u16)(m >> 16))    + b2f((u16)(ts >> 16))    + td1);
    }
    unsigned out = (unsigned)f2b(a0) | ((unsigned)f2b(a1) << 16);
    *(unsigned*)(redb + (size_t)d * 128 + lane * 2) = out;
}

// ---------------------------------------------------------------------------
// out = leaky([H | R] @ Wn) * recv.  H and R both bf16 [M][128].
// ---------------------------------------------------------------------------
__global__ __launch_bounds__(256) void k_gemm_node(
    const u16* __restrict__ H, const u16* __restrict__ R,
    const u16* __restrict__ WT, const float* __restrict__ recvf,
    u16* __restrict__ O16, float* __restrict__ O32, int fin, int M)
{
    __shared__ u16 As[128][72];
    __shared__ u16 Bs[128][72];
    const int t = threadIdx.x;
    const int m0 = blockIdx.x * 128;
    const int w = t >> 6, lane = t & 63, wm = w >> 1, wn = w & 1;
    f32x4 acc[4][4] = {};

    const int row = t >> 1, koff = (t & 1) * 32;
    const int gm_s = m0 + row;

    for (int kt = 0; kt < 256; kt += 64) {
        const u16* Ap = (kt < 128) ? (H + kt) : (R + (kt - 128));
        #pragma unroll
        for (int j = 0; j < 4; ++j) {
            int4 va = make_int4(0, 0, 0, 0);
            if (gm_s < M) va = *(const int4*)(Ap + (size_t)gm_s * 128 + koff + j * 8);
            *(int4*)&As[row][koff + j * 8] = va;
            *(int4*)&Bs[row][koff + j * 8] =
                *(const int4*)(WT + (size_t)row * 256 + kt + koff + j * 8);
        }
        __syncthreads();
        #pragma unroll
        for (int kf = 0; kf < 2; ++kf) {
            s16x8 a[4], b[4];
            #pragma unroll
            for (int mi = 0; mi < 4; ++mi)
                a[mi] = *(const s16x8*)&As[wm * 64 + mi * 16 + (lane & 15)][kf * 32 + (lane >> 4) * 8];
            #pragma unroll
            for (int ni = 0; ni < 4; ++ni)
                b[ni] = *(const s16x8*)&Bs[wn * 64 + ni * 16 + (lane & 15)][kf * 32 + (lane >> 4) * 8];
            #pragma unroll
            for (int mi = 0; mi < 4; ++mi)
                #pragma unroll
                for (int ni = 0; ni < 4; ++ni)
                    acc[mi][ni] = __builtin_amdgcn_mfma_f32_16x16x32_bf16(
                        a[mi], b[ni], acc[mi][ni], 0, 0, 0);
        }
        __syncthreads();
    }
    const int lr = (lane >> 4) * 4, lc = lane & 15;
    #pragma unroll
    for (int mi = 0; mi < 4; ++mi) {
        #pragma unroll
        for (int r = 0; r < 4; ++r) {
            int gm = m0 + wm * 64 + mi * 16 + lr + r;
            if (gm < M) {
                float rv = recvf[gm];
                #pragma unroll
                for (int ni = 0; ni < 4; ++ni) {
                    float val = leaky(acc[mi][ni][r]) * rv;
                    size_t o = (size_t)gm * 128 + wn * 64 + ni * 16 + lc;
                    if (fin) O32[o] = val;
                    else     O16[o] = f2b(val);
                }
            }
        }
    }
}

// ---------------------------------------------------------------------------
extern "C" void kernel_launch(void* const* d_in, const int* in_sizes, int n_in,
                              void* d_out, int out_size, void* d_ws, size_t ws_size,
                              hipStream_t stream)
{
    const float* nf    = (const float*)d_in[0];
    const float* ef    = (const float*)d_in[1];
    const int*   src   = (const int*)d_in[2];
    const int*   dst   = (const int*)d_in[3];
    const int*   ntype = (const int*)d_in[4];
    const float* We[3] = {(const float*)d_in[5], (const float*)d_in[7], (const float*)d_in[9]};
    const float* Wn[3] = {(const float*)d_in[6], (const float*)d_in[8], (const float*)d_in[10]};

    const int N = in_sizes[0] / 128;
    const int E = in_sizes[1] / 64;

    u16* Tsrc = (u16*)d_ws;                        // N*128 (only *tcnt used)
    u16* Tdst = Tsrc + (size_t)N * 128;            // N*128
    u16* hb0  = Tdst + (size_t)N * 128;            // N*128
    u16* hb1  = hb0 + (size_t)N * 128;             // N*128
    u16* redb = hb1 + (size_t)N * 128;             // N*128 bf16
    u16* WTe  = redb + (size_t)N * 128;            // 3*32768
    u16* WTn  = WTe + 3 * 32768;                   // 3*32768
    u16* WTef = WTn + 3 * 32768;                   // 3*8192
    u16* efS  = WTef + 3 * 8192;                   // E*64 (only cnt*64 used)
    u16* msgS = efS + (size_t)E * 64;              // E*128 (only cnt*128 used)
    float* recvf = (float*)(msgS + (size_t)E * 128); // N  } zeroed together
    int* deg    = (int*)(recvf + N);               // N    }
    int* cursor = deg + N;                         // N (becomes segment END)
    int* tflag  = cursor + N;                      // N
    int* trank  = tflag + N;                       // N
    int* tlist  = trank + N;                       // N
    int* bsum   = tlist + N;                       // 256
    int* bsum2  = bsum + 256;                      // 256
    int* cntp   = bsum2 + 256;                     // 1 (+pad)
    int* tcntp  = cntp + 4;                        // 1 (+pad)
    int* eS     = tcntp + 4;                       // E
    int* sSg    = eS + E;                          // E

    const int nb  = (N + 255) / 256;               // 196 <= 256 ok
    const int gEb = (E + 255) / 256;
    const int n4  = N * 128 / 4;

    hipMemsetAsync(recvf, 0, (size_t)N * 2 * sizeof(float), stream);

    k_init<<<(E + N + 255) / 256, 256, 0, stream>>>(src, dst, ntype, deg, recvf, tflag, E, N);
    k_scan1<<<dim3(nb, 2), 256, 0, stream>>>(deg, tflag, bsum, bsum2, N);
    k_scan2<<<2, 256, 0, stream>>>(bsum, bsum2, nb, cntp, tcntp);
    k_scan3<<<dim3(nb, 2), 256, 0, stream>>>(deg, tflag, bsum, bsum2, cursor, trank, tlist, N);
    k_scatter_pos<<<gEb, 256, 0, stream>>>(src, dst, ntype, trank, cursor, eS, sSg, E);
    k_efgather<<<(E + 63) / 64, 256, 0, stream>>>(ef, eS, cntp, efS);
    k_prep<<<(n4 + 3 * 73728 + 255) / 256, 256, 0, stream>>>(
        nf, hb0, n4, We[0], We[1], We[2], Wn[0], Wn[1], Wn[2], WTe, WTn, WTef);

    dim3 gG((N + 127) / 128);
    dim3 gT((N + 127) / 128, 2);
    int  gE = (E + EPB - 1) / EPB;
    int  gR = (N + 3) / 4;

    const u16* hIn[3]  = {hb0, hb1, hb0};
    u16*       hOut[3] = {hb1, hb0, hb1};
    for (int l = 0; l < 3; ++l) {
        int fin = (l == 2);
        k_gemm_T2<<<gT, 256, 0, stream>>>(hIn[l], WTe + (size_t)l * 32768,
                                          Tsrc, Tdst, tlist, tcntp, N);
        k_msg<<<gE, 256, 0, stream>>>(efS, WTef + (size_t)l * 8192, cntp, msgS);
        k_reduce<<<gR, 256, 0, stream>>>(msgS, Tsrc, Tdst, sSg, deg, cursor, redb, N);
        k_gemm_node<<<gG, 256, 0, stream>>>(hIn[l], redb, WTn + (size_t)l * 32768,
                                            recvf, hOut[l], (float*)d_out, fin, N);
    }
}